// Round 1
// baseline (442.955 us; speedup 1.0000x reference)
//
#include <hip/hip_runtime.h>

#define BLOCK 256
#define NB 5      // objects per scene
#define DD 12     // per-object feature dim
#define EE 64     // goal embedding dim
#define HH 32     // F1 hidden dim
#define ROW 81    // D + E + N
#define OUTW 405  // N * ROW

__global__ __launch_bounds__(BLOCK) void fused_relnet_kernel(
    const float* __restrict__ obs, const float* __restrict__ ghat,
    const float* __restrict__ W1, const float* __restrict__ b1,
    const float* __restrict__ W2, const float* __restrict__ b2,
    float* __restrict__ out, int B)
{
    __shared__ float s_w2s[HH];     // rowsum(W2)
    __shared__ float s_sb2;         // sum(b2)
    __shared__ float s_zhat[BLOCK * NB];

    const int tid = threadIdx.x;

    // ---- batch-independent scalars, computed cooperatively ----
    if (tid < HH) {
        float s = 0.f;
        #pragma unroll
        for (int e = 0; e < EE; ++e) s += W2[tid * EE + e];
        s_w2s[tid] = s;
    } else if (tid == HH) {
        float s = 0.f;
        #pragma unroll
        for (int e = 0; e < EE; ++e) s += b2[e];
        s_sb2 = s;
    }
    __syncthreads();

    const int i = blockIdx.x * BLOCK + tid;   // batch index
    const bool valid = (i < B);

    if (valid) {
        // ---- load obs row (60 floats) and ghat row (64 floats) ----
        float o[NB * DD];
        {
            const float4* p = reinterpret_cast<const float4*>(obs + (size_t)i * (NB * DD));
            #pragma unroll
            for (int q = 0; q < NB * DD / 4; ++q) {
                float4 v = p[q];
                o[4*q+0] = v.x; o[4*q+1] = v.y; o[4*q+2] = v.z; o[4*q+3] = v.w;
            }
        }
        float g[EE];
        {
            const float4* p = reinterpret_cast<const float4*>(ghat + (size_t)i * EE);
            #pragma unroll
            for (int q = 0; q < EE / 4; ++q) {
                float4 v = p[q];
                g[4*q+0] = v.x; g[4*q+1] = v.y; g[4*q+2] = v.z; g[4*q+3] = v.w;
            }
        }

        float w[NB * NB];    // attention logits (b2·ghat term dropped: softmax-invariant)
        float hw[NB * NB];   // h · rowsum(W2)  (Zsum minus the sum(b2) constant)
        #pragma unroll
        for (int q = 0; q < NB * NB; ++q) { w[q] = 0.f; hw[q] = 0.f; }

        // ---- accumulate over hidden units, chunks of 8 (loop NOT unrolled: I-cache) ----
        for (int c = 0; c < HH / 8; ++c) {
            float g2[8];     // (W2 @ ghat) chunk
            float w2sc[8];
            #pragma unroll
            for (int hp = 0; hp < 8; ++hp) {
                const int h = c * 8 + hp;
                float acc = 0.f;
                #pragma unroll
                for (int e = 0; e < EE; ++e) acc += W2[h * EE + e] * g[e];
                g2[hp] = acc;
                w2sc[hp] = s_w2s[h];
            }
            #pragma unroll
            for (int hp = 0; hp < 8; ++hp) {
                const int h = c * 8 + hp;
                float a[NB], bb[NB];
                #pragma unroll
                for (int j = 0; j < NB; ++j) {
                    float acc = b1[h];
                    #pragma unroll
                    for (int d = 0; d < DD; ++d) acc += o[j*DD + d] * W1[d*HH + h];
                    a[j] = acc;
                    float accb = 0.f;
                    #pragma unroll
                    for (int d = 0; d < DD; ++d) accb += o[j*DD + d] * W1[(DD + d)*HH + h];
                    bb[j] = accb;
                }
                #pragma unroll
                for (int j = 0; j < NB; ++j) {
                    #pragma unroll
                    for (int k = 0; k < NB; ++k) {
                        float hv = fmaxf(a[j] + bb[k], 0.f);
                        w[j*NB + k]  += hv * g2[hp];
                        hw[j*NB + k] += hv * w2sc[hp];
                    }
                }
            }
        }

        // ---- softmax over 25 pairs + zhat ----
        float m = w[0];
        #pragma unroll
        for (int q = 1; q < NB * NB; ++q) m = fmaxf(m, w[q]);
        float l = 0.f;
        float zacc[NB], racc[NB];
        #pragma unroll
        for (int j = 0; j < NB; ++j) { zacc[j] = 0.f; racc[j] = 0.f; }
        #pragma unroll
        for (int j = 0; j < NB; ++j) {
            #pragma unroll
            for (int k = 0; k < NB; ++k) {
                float e = __expf(w[j*NB + k] - m);
                l += e;
                zacc[j] += e * hw[j*NB + k];
                racc[j] += e;
            }
        }
        const float sb2 = s_sb2;
        const float invl = 1.f / l;
        #pragma unroll
        for (int j = 0; j < NB; ++j)
            s_zhat[tid * NB + j] = (zacc[j] + sb2 * racc[j]) * invl;
    }

    __syncthreads();

    // ---- phase 2: fully-coalesced output write ----
    const size_t base = (size_t)blockIdx.x * BLOCK * OUTW;
    #pragma unroll 4
    for (int t = tid; t < BLOCK * OUTW; t += BLOCK) {
        const int il = t / OUTW;
        const int r405 = t - il * OUTW;
        const int j = r405 / ROW;
        const int r = r405 - j * ROW;
        const int ib = blockIdx.x * BLOCK + il;
        if (ib >= B) break;
        float v;
        if (r < DD)            v = obs[((size_t)ib * NB + j) * DD + r];
        else if (r < DD + EE)  v = ghat[(size_t)ib * EE + (r - DD)];
        else                   v = s_zhat[il * NB + (r - (DD + EE))];
        out[base + t] = v;
    }
}

extern "C" void kernel_launch(void* const* d_in, const int* in_sizes, int n_in,
                              void* d_out, int out_size, void* d_ws, size_t ws_size,
                              hipStream_t stream) {
    const float* obs  = (const float*)d_in[0];
    const float* ghat = (const float*)d_in[1];
    const float* W1   = (const float*)d_in[2];
    const float* b1   = (const float*)d_in[3];
    const float* W2   = (const float*)d_in[4];
    const float* b2   = (const float*)d_in[5];
    float* out = (float*)d_out;

    const int B = in_sizes[0] / (NB * DD);
    const int grid = (B + BLOCK - 1) / BLOCK;
    hipLaunchKernelGGL(fused_relnet_kernel, dim3(grid), dim3(BLOCK), 0, stream,
                       obs, ghat, W1, b1, W2, b2, out, B);
}